// Round 4
// baseline (572.503 us; speedup 1.0000x reference)
//
#include <hip/hip_runtime.h>
#include <hip/hip_bf16.h>

// HardMemory: x[32,512,64,64] f32, memory[1024,512] f32.
// sim = cos(x_pixel, mem_row); out[b,c,n] = memory[argmax][c] * (max>0.8)
// Pipeline (2 kernels): (1) normalize memory -> bf16 in PRE-FRAGMENTED MFMA
// layout, (2) MFMA GEMM + fused max/argmax + fused gather/transpose output.
//
// Ledger (measured):
//  r0-r2: ~300us "scatter residual" was actually fixed harness overhead
//         (re-poison memsets); scatter itself was ~15us. Controllable budget
//         = norm(10us) + simmax.
//  r3: fragmented-B layout: simmax 373->260us. MfmaUtil 22% -> still limited.
//      Arithmetic: A-frag LDS re-reads = 16 MiB/CU = ~82us of LDS BW vs 17us
//      MFMA -> LDS-bandwidth-bound.
//  r4 (this): acc[4][4], mc 4->2 passes: A-LDS traffic halves (41us), B/L2
//      traffic unchanged (each mem row still read once per block). ls
//      transpose row remap kills the 6.3M bank-conflict cycles.

typedef __attribute__((ext_vector_type(8))) short short8;   // 8 bf16 (4 VGPRs)
typedef __attribute__((ext_vector_type(4))) float f32x4;

#define THRESH 0.8f
#define EPSN   1e-12f

__device__ __forceinline__ short f2bf(float f) {
    union { float f; unsigned u; } v; v.f = f;
    unsigned r = v.u + 0x7fffu + ((v.u >> 16) & 1u);   // RNE
    return (short)(r >> 16);
}

// ---------------- kernel 1: normalize memory rows -> fragmented bf16 --------
// memnF layout: for mem-group g=m/16, K-step kks=k/32, quad=(k%32)/8, l15=m%16:
//   memnF[g*8192 + kks*512 + (quad*16+l15)*8 + (k%8)]
// so a wave's B-fragment load for (group, kks) is ONE contiguous 1 KiB:
//   lane (quad*16+l15) reads short8 at [g*8192 + kks*512 + lane*8].
__global__ __launch_bounds__(256) void norm_mem_kernel(
        const float* __restrict__ mem, short* __restrict__ memnF) {
    const int m = blockIdx.x;            // 1024
    const int t = threadIdx.x;           // 256
    const float* r = mem + (size_t)m * 512;
    const float2 v = *(const float2*)&r[2 * t];
    float ss = v.x * v.x + v.y * v.y;
    #pragma unroll
    for (int off = 32; off; off >>= 1) ss += __shfl_down(ss, off, 64);
    __shared__ float part[4];
    __shared__ float rinv_s;
    if ((t & 63) == 0) part[t >> 6] = ss;
    __syncthreads();
    if (t == 0) {
        float s = part[0] + part[1] + part[2] + part[3];
        rinv_s = 1.0f / fmaxf(sqrtf(s), EPSN);
    }
    __syncthreads();
    const float rinv = rinv_s;
    const unsigned u0 = (unsigned short)f2bf(v.x * rinv);
    const unsigned u1 = (unsigned short)f2bf(v.y * rinv);
    const int k0 = t * 2;
    const size_t off = (size_t)(m >> 4) * 8192 + (size_t)(k0 >> 5) * 512
                     + (size_t)((((k0 >> 3) & 3) * 16 + (m & 15)) * 8 + (k0 & 7));
    *(unsigned*)&memnF[off] = u0 | (u1 << 16);
}

// ---------------- kernel 2: GEMM + max/argmax + fused output ----------------
// Block: 64 pixels x all 1024 mems, 512 threads = 8 waves, one shared 64 KiB
// A-tile. Wave tile 64 px x 64 mems (acc[4][4], 16 MFMA per K-step of 32),
// 2 mc passes -> per-wave A-LDS traffic 128 KiB (was 256 KiB at acc[4][2]).
// B register-prefetched one phase ahead (ping-pong via 2-phase kks body).
// kks loop rolled (#pragma unroll 1; full unroll -> VGPR explosion/spill).
// __launch_bounds__(512,4): force combined reg fit for 4 waves/SIMD.
__global__ __launch_bounds__(512, 4) void simmax_kernel(
        const float* __restrict__ x, const short* __restrict__ memnF,
        const float* __restrict__ mem, float* __restrict__ out) {
    __shared__ __align__(16) char smem[66048];   // xs: 64 KiB | ls: 32x516 f32
    short* xs = (short*)smem;
    float (*ls)[516] = (float(*)[516])smem;
    __shared__ float part[8][64];        // per-wave partial ||x||^2
    __shared__ float redv[8][64];        // per-wave max
    __shared__ int   redi[8][64];        // per-wave argmax
    __shared__ int   selp[64];           // final selection per pixel

    const int t  = threadIdx.x;          // 0..511
    const int b  = blockIdx.y;           // 32
    const int n0 = blockIdx.x * 64;      // 64 pixel tiles
    const int p  = t & 63;
    const int w  = t >> 6;               // wave 0..7

    // ---- stage X tile: x[b, c, n0+p] -> xs[(c/8)*64 + p][c%8] as bf16 ----
    const float* xb = x + ((size_t)b * 512) * 4096 + n0 + p;
    float ss = 0.f;
    for (int oct = w; oct < 64; oct += 8) {
        short8 pk;
        #pragma unroll
        for (int i = 0; i < 8; ++i) {
            float v = xb[(size_t)(oct * 8 + i) * 4096];
            ss += v * v;
            pk[i] = f2bf(v);
        }
        *(short8*)&xs[(oct * 64 + p) * 8] = pk;
    }
    part[w][p] = ss;
    __syncthreads();

    float xnorm_reg = 1.0f;
    if (t < 64) {
        float s = part[0][t];
        #pragma unroll
        for (int ww = 1; ww < 8; ++ww) s += part[ww][t];
        xnorm_reg = fmaxf(sqrtf(s), EPSN);
    }

    const int lane = t & 63;
    const int quad = lane >> 4;
    const int l15  = lane & 15;

    float runv[4][4];
    int   runi[4][4];
    #pragma unroll
    for (int i = 0; i < 4; ++i)
        #pragma unroll
        for (int r = 0; r < 4; ++r) { runv[i][r] = -1e30f; runi[i][r] = 0; }

    #pragma unroll 1
    for (int mc = 0; mc < 2; ++mc) {
        f32x4 acc[4][4];
        #pragma unroll
        for (int i = 0; i < 4; ++i)
            #pragma unroll
            for (int j = 0; j < 4; ++j) acc[i][j] = (f32x4){0.f, 0.f, 0.f, 0.f};

        const int mb = mc * 512 + w * 64;          // this wave's 64 mems
        const int g0 = mb >> 4;                    // 16-mem fragment group
        const short* bb = memnF + (size_t)g0 * 8192 + lane * 8;

        short8 bA[4], bB[4];
        #pragma unroll
        for (int j = 0; j < 4; ++j)                // contiguous 1 KiB each
            bA[j] = *(const short8*)(bb + j * 8192);

        #pragma unroll 1
        for (int kks = 0; kks < 16; kks += 2) {
            // phase A: prefetch kks+1, compute kks
            #pragma unroll
            for (int j = 0; j < 4; ++j)
                bB[j] = *(const short8*)(bb + j * 8192 + (kks + 1) * 512);
            {
                const int oct = kks * 4 + quad;
                short8 a[4];
                #pragma unroll
                for (int i = 0; i < 4; ++i)
                    a[i] = *(const short8*)&xs[(oct * 64 + i * 16 + l15) * 8];
                #pragma unroll
                for (int i = 0; i < 4; ++i)
                    #pragma unroll
                    for (int j = 0; j < 4; ++j)
                        acc[i][j] = __builtin_amdgcn_mfma_f32_16x16x32_bf16(
                            a[i], bA[j], acc[i][j], 0, 0, 0);
            }
            // phase B: prefetch kks+2 (wraps to 0 on last iter, in-bounds,
            // values unused), compute kks+1
            const int kn = (kks + 2) & 15;
            #pragma unroll
            for (int j = 0; j < 4; ++j)
                bA[j] = *(const short8*)(bb + j * 8192 + kn * 512);
            {
                const int oct = (kks + 1) * 4 + quad;
                short8 a[4];
                #pragma unroll
                for (int i = 0; i < 4; ++i)
                    a[i] = *(const short8*)&xs[(oct * 64 + i * 16 + l15) * 8];
                #pragma unroll
                for (int i = 0; i < 4; ++i)
                    #pragma unroll
                    for (int j = 0; j < 4; ++j)
                        acc[i][j] = __builtin_amdgcn_mfma_f32_16x16x32_bf16(
                            a[i], bB[j], acc[i][j], 0, 0, 0);
            }
        }

        #pragma unroll
        for (int i = 0; i < 4; ++i)
            #pragma unroll
            for (int j = 0; j < 4; ++j) {        // ascending col within wave
                const int cb = mb + j * 16 + l15;
                #pragma unroll
                for (int r = 0; r < 4; ++r) {
                    float v = acc[i][j][r];
                    if (v > runv[i][r]) { runv[i][r] = v; runi[i][r] = cb; }
                }
            }
    }

    // ---- cross-lane max/argmax (cols live on 16 lanes of each quad) ----
    #pragma unroll
    for (int i = 0; i < 4; ++i)
        #pragma unroll
        for (int r = 0; r < 4; ++r) {
            float v = runv[i][r]; int ix = runi[i][r];
            #pragma unroll
            for (int off = 1; off < 16; off <<= 1) {
                float ov = __shfl_xor(v, off, 64);
                int   oi = __shfl_xor(ix, off, 64);
                if (ov > v || (ov == v && oi < ix)) { v = ov; ix = oi; }
            }
            if (l15 == 0) {
                const int pl = i * 16 + quad * 4 + r;   // pixel row 0..63
                redv[w][pl] = v;
                redi[w][pl] = ix;
            }
        }

    __syncthreads();
    if (t < 64) {
        float v = redv[0][t]; int ix = redi[0][t];
        #pragma unroll
        for (int c = 1; c < 8; ++c) {            // index-based tie-break
            float ov = redv[c][t]; int oi = redi[c][t];
            if (ov > v || (ov == v && oi < ix)) { v = ov; ix = oi; }
        }
        float maxval = v / xnorm_reg;
        selp[t] = (maxval > THRESH) ? ix : -1;
    }
    __syncthreads();                      // selp ready; xs reads all done

    // ---- fused gather + transpose output: two halves of 32 pixels ----
    // Row remap rr(p) = (p&3)*8 + (p>>2): transpose-read banks become
    // (4j+cl+c0)%32 -> 2-way (free, m136). r3 had rr=p: 4-way, 6.3M conflict
    // cycles. Gather: full-wave f32x4 row reads (L2-hot). Write: 8 channels x
    // 128 B contiguous per instr.
    #pragma unroll 1
    for (int half = 0; half < 2; ++half) {
        #pragma unroll
        for (int pr = 0; pr < 4; ++pr) {
            const int pp = w * 4 + pr;               // pixel in half: 0..31
            const int rr = ((pp & 3) << 3) | (pp >> 2);
            const int s = selp[half * 32 + pp];
            if (s < 0) {
                *(f32x4*)&ls[rr][lane * 4]       = (f32x4){0.f, 0.f, 0.f, 0.f};
                *(f32x4*)&ls[rr][lane * 4 + 256] = (f32x4){0.f, 0.f, 0.f, 0.f};
            } else {
                const float* r = mem + (size_t)s * 512;
                *(f32x4*)&ls[rr][lane * 4]       = *(const f32x4*)&r[lane * 4];
                *(f32x4*)&ls[rr][lane * 4 + 256] = *(const f32x4*)&r[lane * 4 + 256];
            }
        }
        __syncthreads();
        const int cl = lane >> 3;            // 0..7: channel within pass
        const int j8 = lane & 7;             // pixel quad group: pixels 4j..4j+3
        #pragma unroll
        for (int cp = 0; cp < 8; ++cp) {
            const int c = w * 64 + cp * 8 + cl;
            f32x4 v;                          // pixel p=4*j8+k lives in row k*8+j8
            v.x = ls[0 * 8 + j8][c];
            v.y = ls[1 * 8 + j8][c];
            v.z = ls[2 * 8 + j8][c];
            v.w = ls[3 * 8 + j8][c];
            *(f32x4*)&out[((size_t)b * 512 + c) * 4096 + n0 + half * 32 + j8 * 4] = v;
        }
        __syncthreads();
    }
}

extern "C" void kernel_launch(void* const* d_in, const int* in_sizes, int n_in,
                              void* d_out, int out_size, void* d_ws, size_t ws_size,
                              hipStream_t stream) {
    const float* x   = (const float*)d_in[0];   // [32,512,64,64]
    const float* mem = (const float*)d_in[1];   // [1024,512]
    short* memnF = (short*)d_ws;                // 1 MiB fragmented bf16
    float* out   = (float*)d_out;

    norm_mem_kernel<<<dim3(1024), dim3(256), 0, stream>>>(mem, memnF);
    simmax_kernel<<<dim3(64, 32), dim3(512), 0, stream>>>(x, memnF, mem, out);
}